// Round 3
// baseline (864.260 us; speedup 1.0000x reference)
//
#include <hip/hip_runtime.h>
#include <math.h>

#define N_TOK 8192
#define DIM   1024
#define HID   2048
#define NE    8
#define NPAIR (N_TOK * 2)          // 16384 (token, expert) pairs exactly
#define CAP   (NPAIR + 128)        // pad so last row-tile reads stay in bounds
#define TAIL  (N_TOK * DIM)        // offset of scalar outputs in d_out

typedef __bf16 bf16x8_t __attribute__((ext_vector_type(8)));
typedef float  f32x4_t  __attribute__((ext_vector_type(4)));

__device__ __forceinline__ unsigned short f2bf(float f) {
  union { float f; unsigned u; } v; v.f = f;
  unsigned r = v.u + 0x7fffu + ((v.u >> 16) & 1u);   // RNE
  return (unsigned short)(r >> 16);
}

__device__ __forceinline__ float bf2f(unsigned short h) {
  union { unsigned u; float f; } v; v.u = ((unsigned)h) << 16;
  return v.f;
}

__device__ __forceinline__ float gelu_exact(float v) {
  return 0.5f * v * (1.f + erff(v * 0.70710678118654752440f));
}

// async global->LDS DMA, 16B/lane. LDS side is wave-uniform base + lane*16
// (m104/m108 semantics) — callers pass a uniform LDS chunk base.
__device__ __forceinline__ void load16_lds(const void* g, void* l) {
  __builtin_amdgcn_global_load_lds(
      (const __attribute__((address_space(1))) unsigned int*)g,
      (__attribute__((address_space(3))) unsigned int*)l, 16, 0, 0);
}

// ---------------- x -> bf16 ----------------
__global__ __launch_bounds__(256) void cvt_x_kernel(const float* __restrict__ x,
                                                    unsigned short* __restrict__ xbf) {
  size_t base = (size_t)(blockIdx.x * 256 + threadIdx.x) * 4;
  float4 v = *(const float4*)(x + base);
  ushort4 o;
  o.x = f2bf(v.x); o.y = f2bf(v.y); o.z = f2bf(v.z); o.w = f2bf(v.w);
  *(ushort4*)(xbf + base) = o;
}

// ---------------- fp32 [z][R][C] -> bf16 [z][C][R] (LDS-tiled) ----------------
__global__ __launch_bounds__(256) void transpose_kernel(const float* __restrict__ src,
                                                        unsigned short* __restrict__ dst,
                                                        int R, int C) {
  __shared__ float tile[32][33];
  int z = blockIdx.z;
  const float* s = src + (size_t)z * R * C;
  unsigned short* d = dst + (size_t)z * R * C;
  int c0 = blockIdx.x * 32, r0 = blockIdx.y * 32;
  int tx = threadIdx.x & 31, ty = threadIdx.x >> 5;   // 32 x 8
  #pragma unroll
  for (int i = 0; i < 32; i += 8)
    tile[ty + i][tx] = s[(size_t)(r0 + ty + i) * C + c0 + tx];
  __syncthreads();
  #pragma unroll
  for (int i = 0; i < 32; i += 8)
    d[(size_t)(c0 + ty + i) * R + r0 + tx] = f2bf(tile[tx][ty + i]);
}

// ---------------- router: logits (fp32), top-2, softmax, aux stats ----------------
#define R_BLOCKS 128
#define R_TPW    (N_TOK / (R_BLOCKS * 4))   // 16 tokens per wave
__global__ __launch_bounds__(256) void router_kernel(
    const float* __restrict__ x, const float* __restrict__ gW, const float* __restrict__ gb,
    int* __restrict__ tok_e, float* __restrict__ tok_g,
    int* __restrict__ cnt, float* __restrict__ imp, float* __restrict__ ent_sum) {
  __shared__ int s_cnt[NE];
  __shared__ float s_imp[NE];
  __shared__ float s_ent;
  int tid = threadIdx.x;
  if (tid < NE) { s_cnt[tid] = 0; s_imp[tid] = 0.f; }
  if (tid == 0) s_ent = 0.f;
  __syncthreads();
  int wid = tid >> 6, lane = tid & 63;
  int t0 = (blockIdx.x * 4 + wid) * R_TPW;
  float imp_loc[8] = {0.f, 0.f, 0.f, 0.f, 0.f, 0.f, 0.f, 0.f};
  float ent_loc = 0.f;
  for (int t = 0; t < R_TPW; ++t) {
    int n = t0 + t;
    const float* xr = x + (size_t)n * DIM;
    float p[8] = {0.f, 0.f, 0.f, 0.f, 0.f, 0.f, 0.f, 0.f};
    #pragma unroll
    for (int it = 0; it < DIM / 64; ++it) {
      int d = lane + (it << 6);
      float xv = xr[d];
      const float4* g4 = (const float4*)(gW + (size_t)d * NE);
      float4 a = g4[0], b = g4[1];
      p[0] += xv * a.x; p[1] += xv * a.y; p[2] += xv * a.z; p[3] += xv * a.w;
      p[4] += xv * b.x; p[5] += xv * b.y; p[6] += xv * b.z; p[7] += xv * b.w;
    }
    #pragma unroll
    for (int e = 0; e < 8; ++e)
      for (int o = 32; o > 0; o >>= 1) p[e] += __shfl_down(p[e], o, 64);
    if (lane == 0) {
      float lg[8];
      #pragma unroll
      for (int e = 0; e < 8; ++e) lg[e] = p[e] + gb[e];
      int i0 = 0;
      #pragma unroll
      for (int e = 1; e < 8; ++e) if (lg[e] > lg[i0]) i0 = e;   // ties -> lowest idx
      int i1 = (i0 == 0) ? 1 : 0;
      #pragma unroll
      for (int e = 0; e < 8; ++e) if (e != i0 && lg[e] > lg[i1]) i1 = e;
      float d1 = expf(lg[i1] - lg[i0]);
      float g0 = 1.f / (1.f + d1);
      float g1 = d1 * g0;
      tok_e[2 * n] = i0; tok_e[2 * n + 1] = i1;
      tok_g[2 * n] = g0; tok_g[2 * n + 1] = g1;
      atomicAdd(&s_cnt[i0], 1);
      atomicAdd(&s_cnt[i1], 1);
      float mx = lg[i0], s = 0.f, pe[8];
      #pragma unroll
      for (int e = 0; e < 8; ++e) { pe[e] = expf(lg[e] - mx); s += pe[e]; }
      float inv = 1.f / s;
      #pragma unroll
      for (int e = 0; e < 8; ++e) {
        float pr = pe[e] * inv;
        imp_loc[e] += pr;
        ent_loc -= pr * logf(pr + 1e-8f);
      }
    }
  }
  if (lane == 0) {
    #pragma unroll
    for (int e = 0; e < 8; ++e) atomicAdd(&s_imp[e], imp_loc[e]);
    atomicAdd(&s_ent, ent_loc);
  }
  __syncthreads();
  const float invN = 1.f / (float)N_TOK;
  if (tid < NE) {
    atomicAdd(&cnt[tid], s_cnt[tid]);
    atomicAdd(&imp[tid], s_imp[tid] * invN);
  }
  if (tid == NE) atomicAdd(ent_sum, s_ent * invN);
}

// ---------------- finalize: offsets/cursors + scalar outputs ----------------
__global__ void finalize_kernel(const int* __restrict__ cnt, int* __restrict__ offs,
                                int* __restrict__ cursor, const float* __restrict__ imp,
                                const float* __restrict__ ent_sum, float* __restrict__ out_tail) {
  if (threadIdx.x == 0) {
    int off = 0; float bal = 0.f, util = 0.f;
    for (int e = 0; e < NE; ++e) {
      offs[e] = off; cursor[e] = off; off += cnt[e];
      float ld = (float)cnt[e] * (1.f / (float)N_TOK);
      float im = imp[e];
      out_tail[3 + e] = ld;        // load
      out_tail[11 + e] = im;       // importance
      bal += im * ld;
      util -= ld * logf(ld + 1e-8f);
    }
    out_tail[0] = (float)NE * bal; // balance_loss
    out_tail[1] = *ent_sum;        // entropy
    out_tail[2] = util;            // utilization_entropy
  }
}

// ---------------- scatter pairs into expert buckets ----------------
__global__ __launch_bounds__(256) void scatter_kernel(
    const int* __restrict__ tok_e, const float* __restrict__ tok_g,
    int* __restrict__ cursor, int* __restrict__ row_token, float* __restrict__ row_gate,
    int* __restrict__ pair_slot) {
  __shared__ int s_cnt[NE], s_base[NE], s_rank[NE];
  int tid = threadIdx.x;
  if (tid < NE) { s_cnt[tid] = 0; s_rank[tid] = 0; }
  __syncthreads();
  int n = blockIdx.x * 256 + tid;
  int e0 = tok_e[2 * n], e1 = tok_e[2 * n + 1];
  atomicAdd(&s_cnt[e0], 1);
  atomicAdd(&s_cnt[e1], 1);
  __syncthreads();
  if (tid < NE) s_base[tid] = atomicAdd(&cursor[tid], s_cnt[tid]);
  __syncthreads();
  int r0 = atomicAdd(&s_rank[e0], 1);
  int s0 = s_base[e0] + r0;
  row_token[s0] = n; row_gate[s0] = tok_g[2 * n]; pair_slot[2 * n] = s0;
  int r1 = atomicAdd(&s_rank[e1], 1);
  int s1 = s_base[e1] + r1;
  row_token[s1] = n; row_gate[s1] = tok_g[2 * n + 1]; pair_slot[2 * n + 1] = s1;
}

// =======================================================================
// R3 GEMM structure (m97-style): fragment-order LDS tiles.
// A/B tile = 128 rows x 64 k, stored as 16 chunks of 1KB; chunk cb holds
// rows rb*16..rb*16+15 (rb=cb>>1), k-half ks32=cb&1 (32 k). Within a chunk,
// lane l = q*16+m16 owns 16B: row m16, k = ks32*32 + q*8 .. +7. This is
// simultaneously the global_load_lds lane order (uniform base + lane*16)
// AND the MFMA fragment read order (ds_read_b128 sequential -> 0 bank
// conflicts, vs 8.65M conflict-cycles with the R2 padded row-major tile).
// =======================================================================

// ---------------- GEMM1: He = gelu(X_gather @ W1[e] + b1[e]), bf16 out ----------------
__global__ __launch_bounds__(256, 2) void expert_gemm1(
    const unsigned short* __restrict__ xbf,   // [N][D] bf16
    const unsigned short* __restrict__ W1T,   // [E][H][D] bf16
    const float* __restrict__ b1,             // [E][H]
    const int* __restrict__ cnt, const int* __restrict__ offs,
    const int* __restrict__ row_token,
    unsigned short* __restrict__ He) {        // [CAP][H] bf16
  __shared__ __align__(16) unsigned short As[8192];   // 16KB, fragment order
  __shared__ __align__(16) unsigned short Bs[8192];
  __shared__ int toks[128];
  int e = blockIdx.z;
  int c_e = cnt[e];
  int row0 = blockIdx.x * 128;
  if (row0 >= c_e) return;
  int col0 = blockIdx.y * 128;
  int off = offs[e];
  int tid = threadIdx.x;
  if (tid < 128) {
    int r = row0 + tid;
    toks[tid] = (r < c_e) ? row_token[off + r] : 0;
  }
  __syncthreads();
  int wid = tid >> 6, lane = tid & 63;
  int m16 = lane & 15, q = lane >> 4;
  int wr = (wid & 1) << 6, wc = (wid >> 1) << 6;
  const unsigned short* Bg = W1T + (size_t)e * HID * DIM;
  // per-wave staging pointers: wave wid handles chunks cb = wid*4+t
  const unsigned short* gA[4]; const unsigned short* gB[4];
  unsigned short* lA[4]; unsigned short* lB[4];
  #pragma unroll
  for (int t = 0; t < 4; ++t) {
    int cb = wid * 4 + t, rb = cb >> 1, ks32 = cb & 1;
    gA[t] = xbf + (size_t)toks[rb * 16 + m16] * DIM + ks32 * 32 + q * 8;
    gB[t] = Bg + (size_t)(col0 + rb * 16 + m16) * DIM + ks32 * 32 + q * 8;
    lA[t] = As + cb * 512;   // uniform across lanes (chunk base)
    lB[t] = Bs + cb * 512;
  }
  f32x4_t zero4 = {0.f, 0.f, 0.f, 0.f};
  f32x4_t acc[4][4];
  #pragma unroll
  for (int i = 0; i < 4; ++i)
    #pragma unroll
    for (int j = 0; j < 4; ++j) acc[i][j] = zero4;
  int ra = wr >> 4, rb_ = wc >> 4;
  for (int k0 = 0; k0 < DIM; k0 += 64) {
    #pragma unroll
    for (int t = 0; t < 4; ++t) {
      load16_lds(gA[t] + k0, lA[t]);
      load16_lds(gB[t] + k0, lB[t]);
    }
    __syncthreads();   // drains vmcnt (global_load_lds) before reads
    #pragma unroll
    for (int ks32 = 0; ks32 < 2; ++ks32) {
      bf16x8_t a[4], b[4];
      #pragma unroll
      for (int i = 0; i < 4; ++i) {
        a[i] = *(const bf16x8_t*)&As[((ra + i) * 2 + ks32) * 512 + lane * 8];
        b[i] = *(const bf16x8_t*)&Bs[((rb_ + i) * 2 + ks32) * 512 + lane * 8];
      }
      #pragma unroll
      for (int i = 0; i < 4; ++i)
        #pragma unroll
        for (int j = 0; j < 4; ++j)
          acc[i][j] = __builtin_amdgcn_mfma_f32_16x16x32_bf16(a[i], b[j], acc[i][j], 0, 0, 0);
    }
    __syncthreads();
  }
  const float* b1e = b1 + (size_t)e * HID;
  #pragma unroll
  for (int i = 0; i < 4; ++i) {
    #pragma unroll
    for (int r = 0; r < 4; ++r) {
      int row = wr + i * 16 + q * 4 + r;
      if (row0 + row < c_e) {
        size_t slot = (size_t)(off + row0 + row);
        #pragma unroll
        for (int j = 0; j < 4; ++j) {
          int col = col0 + wc + j * 16 + m16;
          float v = acc[i][j][r] + b1e[col];
          He[slot * HID + col] = f2bf(gelu_exact(v));
        }
      }
    }
  }
}

// ---------------- GEMM2: y[slot] = He @ W2[e]  (raw, bf16; bias+gate in LN) ----------------
__global__ __launch_bounds__(256, 2) void expert_gemm2(
    const unsigned short* __restrict__ He,    // [CAP][H] bf16
    const unsigned short* __restrict__ W2T,   // [E][D][H] bf16
    const int* __restrict__ cnt, const int* __restrict__ offs,
    unsigned short* __restrict__ yb) {        // [CAP][D] bf16
  __shared__ __align__(16) unsigned short As[8192];
  __shared__ __align__(16) unsigned short Bs[8192];
  int e = blockIdx.z;
  int c_e = cnt[e];
  int row0 = blockIdx.x * 128;
  if (row0 >= c_e) return;
  int col0 = blockIdx.y * 128;
  int off = offs[e];
  int tid = threadIdx.x;
  int wid = tid >> 6, lane = tid & 63;
  int m16 = lane & 15, q = lane >> 4;
  int wr = (wid & 1) << 6, wc = (wid >> 1) << 6;
  const unsigned short* Ag = He + (size_t)(off + row0) * HID;
  const unsigned short* Bg = W2T + (size_t)e * DIM * HID;
  const unsigned short* gA[4]; const unsigned short* gB[4];
  unsigned short* lA[4]; unsigned short* lB[4];
  #pragma unroll
  for (int t = 0; t < 4; ++t) {
    int cb = wid * 4 + t, rb = cb >> 1, ks32 = cb & 1;
    gA[t] = Ag + (size_t)(rb * 16 + m16) * HID + ks32 * 32 + q * 8;
    gB[t] = Bg + (size_t)(col0 + rb * 16 + m16) * HID + ks32 * 32 + q * 8;
    lA[t] = As + cb * 512;
    lB[t] = Bs + cb * 512;
  }
  f32x4_t zero4 = {0.f, 0.f, 0.f, 0.f};
  f32x4_t acc[4][4];
  #pragma unroll
  for (int i = 0; i < 4; ++i)
    #pragma unroll
    for (int j = 0; j < 4; ++j) acc[i][j] = zero4;
  int ra = wr >> 4, rb_ = wc >> 4;
  for (int k0 = 0; k0 < HID; k0 += 64) {
    #pragma unroll
    for (int t = 0; t < 4; ++t) {
      load16_lds(gA[t] + k0, lA[t]);
      load16_lds(gB[t] + k0, lB[t]);
    }
    __syncthreads();
    #pragma unroll
    for (int ks32 = 0; ks32 < 2; ++ks32) {
      bf16x8_t a[4], b[4];
      #pragma unroll
      for (int i = 0; i < 4; ++i) {
        a[i] = *(const bf16x8_t*)&As[((ra + i) * 2 + ks32) * 512 + lane * 8];
        b[i] = *(const bf16x8_t*)&Bs[((rb_ + i) * 2 + ks32) * 512 + lane * 8];
      }
      #pragma unroll
      for (int i = 0; i < 4; ++i)
        #pragma unroll
        for (int j = 0; j < 4; ++j)
          acc[i][j] = __builtin_amdgcn_mfma_f32_16x16x32_bf16(a[i], b[j], acc[i][j], 0, 0, 0);
    }
    __syncthreads();
  }
  #pragma unroll
  for (int i = 0; i < 4; ++i) {
    #pragma unroll
    for (int r = 0; r < 4; ++r) {
      int row = wr + i * 16 + q * 4 + r;
      if (row0 + row < c_e) {
        size_t slot = (size_t)(off + row0 + row);
        #pragma unroll
        for (int j = 0; j < 4; ++j) {
          int col = col0 + wc + j * 16 + m16;
          yb[slot * DIM + col] = f2bf(acc[i][j][r]);
        }
      }
    }
  }
}

// ---------------- gather + gate + bias + residual + LayerNorm ----------------
__global__ __launch_bounds__(256) void ln_kernel(
    const float* __restrict__ x, const unsigned short* __restrict__ yb,
    const int* __restrict__ tok_e, const float* __restrict__ tok_g,
    const int* __restrict__ pair_slot, const float* __restrict__ b2,
    const float* __restrict__ gamma, const float* __restrict__ beta,
    float* __restrict__ out) {
  int n = blockIdx.x, tid = threadIdx.x;
  int e0 = tok_e[2 * n], e1 = tok_e[2 * n + 1];
  float g0 = tok_g[2 * n], g1 = tok_g[2 * n + 1];
  size_t s0 = (size_t)pair_slot[2 * n], s1 = (size_t)pair_slot[2 * n + 1];
  const float* xr = x + (size_t)n * DIM;
  const unsigned short* y0 = yb + s0 * DIM;
  const unsigned short* y1 = yb + s1 * DIM;
  const float* b2e0 = b2 + (size_t)e0 * DIM;
  const float* b2e1 = b2 + (size_t)e1 * DIM;
  float z[4], s = 0.f, s2 = 0.f;
  #pragma unroll
  for (int jj = 0; jj < 4; ++jj) {
    int d = tid + (jj << 8);
    float v = xr[d] + g0 * (bf2f(y0[d]) + b2e0[d]) + g1 * (bf2f(y1[d]) + b2e1[d]);
    z[jj] = v; s += v; s2 += v * v;
  }
  for (int o = 32; o > 0; o >>= 1) { s += __shfl_down(s, o, 64); s2 += __shfl_down(s2, o, 64); }
  __shared__ float rs[4], rs2[4];
  int wid = tid >> 6, lane = tid & 63;
  if (lane == 0) { rs[wid] = s; rs2[wid] = s2; }
  __syncthreads();
  float ts = rs[0] + rs[1] + rs[2] + rs[3];
  float ts2 = rs2[0] + rs2[1] + rs2[2] + rs2[3];
  float mu = ts * (1.f / DIM);
  float var = ts2 * (1.f / DIM) - mu * mu;
  float rstd = rsqrtf(var + 1e-5f);
  float* orow = out + (size_t)n * DIM;
  #pragma unroll
  for (int jj = 0; jj < 4; ++jj) {
    int d = tid + (jj << 8);
    orow[d] = (z[jj] - mu) * rstd * gamma[d] + beta[d];
  }
}

extern "C" void kernel_launch(void* const* d_in, const int* in_sizes, int n_in,
                              void* d_out, int out_size, void* d_ws, size_t ws_size,
                              hipStream_t stream) {
  const float* x     = (const float*)d_in[0];
  const float* gW    = (const float*)d_in[1];
  const float* gb    = (const float*)d_in[2];
  const float* W1    = (const float*)d_in[3];
  const float* b1    = (const float*)d_in[4];
  const float* W2    = (const float*)d_in[5];
  const float* b2    = (const float*)d_in[6];
  const float* gamma = (const float*)d_in[7];
  const float* beta  = (const float*)d_in[8];
  float* out = (float*)d_out;

  // workspace layout (~182 MB), all chunks 16B-aligned
  char* w = (char*)d_ws;
  unsigned short* xbf = (unsigned short*)w; w += (size_t)N_TOK * DIM * 2;
  unsigned short* W1T = (unsigned short*)w; w += (size_t)NE * HID * DIM * 2;
  unsigned short* W2T = (unsigned short*)w; w += (size_t)NE * DIM * HID * 2;
  unsigned short* He  = (unsigned short*)w; w += (size_t)CAP * HID * 2;
  unsigned short* yb  = (unsigned short*)w; w += (size_t)CAP * DIM * 2;
  int*   row_token    = (int*)w;            w += (size_t)CAP * 4;
  float* row_gate     = (float*)w;          w += (size_t)CAP * 4;
  int*   tok_e        = (int*)w;            w += (size_t)NPAIR * 4;
  float* tok_g        = (float*)w;          w += (size_t)NPAIR * 4;
  int*   pair_slot    = (int*)w;            w += (size_t)NPAIR * 4;
  float* imp          = (float*)w;          // 8 floats
  float* ent_sum      = imp + 8;            // 1 float (+7 pad)
  int*   cntp         = (int*)(imp + 16);   // 8 ints
  int*   cursor       = cntp + 8;           // 8 ints
  int*   offs         = cursor + 8;         // 8 ints

  hipMemsetAsync(imp, 0, 256, stream);      // imp, ent_sum, cnt (cursor/offs set by finalize)

  cvt_x_kernel<<<N_TOK * DIM / (256 * 4), 256, 0, stream>>>(x, xbf);
  transpose_kernel<<<dim3(HID / 32, DIM / 32, NE), 256, 0, stream>>>(W1, W1T, DIM, HID);
  transpose_kernel<<<dim3(DIM / 32, HID / 32, NE), 256, 0, stream>>>(W2, W2T, HID, DIM);
  router_kernel<<<R_BLOCKS, 256, 0, stream>>>(x, gW, gb, tok_e, tok_g, cntp, imp, ent_sum);
  finalize_kernel<<<1, 64, 0, stream>>>(cntp, offs, cursor, imp, ent_sum, out + TAIL);
  scatter_kernel<<<N_TOK / 256, 256, 0, stream>>>(tok_e, tok_g, cursor, row_token, row_gate, pair_slot);
  expert_gemm1<<<dim3(64, HID / 128, NE), 256, 0, stream>>>(xbf, W1T, b1, cntp, offs, row_token, He);
  expert_gemm2<<<dim3(64, DIM / 128, NE), 256, 0, stream>>>(He, W2T, cntp, offs, yb);
  ln_kernel<<<N_TOK, 256, 0, stream>>>(x, yb, tok_e, tok_g, pair_slot, b2, gamma, beta, out);
}

// Round 4
// 523.000 us; speedup vs baseline: 1.6525x; 1.6525x over previous
//
#include <hip/hip_runtime.h>
#include <math.h>

#define N_TOK 8192
#define DIM   1024
#define HID   2048
#define NE    8
#define NPAIR (N_TOK * 2)          // 16384 (token, expert) pairs exactly
#define CAPP  (NPAIR + NE * 128)   // 17408: expert regions padded to 128 rows
#define TAIL  (N_TOK * DIM)        // offset of scalar outputs in d_out

typedef __bf16 bf16x8_t __attribute__((ext_vector_type(8)));
typedef float  f32x4_t  __attribute__((ext_vector_type(4)));

__device__ __forceinline__ unsigned short f2bf(float f) {
  union { float f; unsigned u; } v; v.f = f;
  unsigned r = v.u + 0x7fffu + ((v.u >> 16) & 1u);   // RNE
  return (unsigned short)(r >> 16);
}

__device__ __forceinline__ float bf2f(unsigned short h) {
  union { unsigned u; float f; } v; v.u = ((unsigned)h) << 16;
  return v.f;
}

__device__ __forceinline__ float gelu_exact(float v) {
  return 0.5f * v * (1.f + erff(v * 0.70710678118654752440f));
}

// async global->LDS DMA, 16B/lane; LDS base wave-uniform, HW scatters lane*16.
__device__ __forceinline__ void load16_lds(const void* g, void* l) {
  __builtin_amdgcn_global_load_lds(
      (const __attribute__((address_space(1))) unsigned int*)g,
      (__attribute__((address_space(3))) unsigned int*)l, 16, 0, 0);
}

// =======================================================================
// Fragment-chunk global layout (R4): a matrix [R rows][Kd k] is stored as
// 1KB chunks; chunk c = (r>>4)*(Kd/32) + (k>>5); within a chunk, lane
// l = (k>>3&3)*16 + (r&15) owns 16B = 8 shorts (k&7 fastest). A GEMM tile
// stage is then ONE contiguous-1KB global_load_lds per chunk (m97-grade
// coalescing) and fragment ds_read_b128 is sequential (0 bank conflicts,
// proven R3). Producers write this layout directly: w_to_frag (weights),
// gather_a1 (bucketed activations), gemm1 epilogue (He for gemm2).
// =======================================================================

// ---------------- weights fp32 [z][Kd][R] -> frag-chunk bf16 ----------------
template<int KD, int RR>
__global__ __launch_bounds__(256) void w_to_frag(const float* __restrict__ src,
                                                 unsigned short* __restrict__ dst) {
  constexpr int KD32 = KD / 32;
  int z = blockIdx.z;
  int cl = blockIdx.x * 4 + (threadIdx.x >> 6);   // chunk id (grid sized exactly)
  int lane = threadIdx.x & 63, m16 = lane & 15, q = lane >> 4;
  int rblk = cl / KD32, kblk = cl % KD32;         // pow2 -> shifts
  int r = rblk * 16 + m16;
  int kb = kblk * 32 + q * 8;
  const float* s = src + (size_t)z * KD * RR + (size_t)kb * RR + r;
  unsigned short t[8];
  #pragma unroll
  for (int j = 0; j < 8; ++j) t[j] = f2bf(s[(size_t)j * RR]);
  *(uint4*)(dst + (size_t)z * KD * RR + (size_t)cl * 512 + lane * 8) = *(uint4*)t;
}

// ---------------- router: logits (fp32), top-2, softmax, aux stats ----------------
#define R_BLOCKS 128
#define R_TPW    (N_TOK / (R_BLOCKS * 4))   // 16 tokens per wave
__global__ __launch_bounds__(256) void router_kernel(
    const float* __restrict__ x, const float* __restrict__ gW, const float* __restrict__ gb,
    int* __restrict__ tok_e, float* __restrict__ tok_g,
    int* __restrict__ cnt, float* __restrict__ imp, float* __restrict__ ent_sum) {
  __shared__ int s_cnt[NE];
  __shared__ float s_imp[NE];
  __shared__ float s_ent;
  int tid = threadIdx.x;
  if (tid < NE) { s_cnt[tid] = 0; s_imp[tid] = 0.f; }
  if (tid == 0) s_ent = 0.f;
  __syncthreads();
  int wid = tid >> 6, lane = tid & 63;
  int t0 = (blockIdx.x * 4 + wid) * R_TPW;
  float imp_loc[8] = {0.f, 0.f, 0.f, 0.f, 0.f, 0.f, 0.f, 0.f};
  float ent_loc = 0.f;
  for (int t = 0; t < R_TPW; ++t) {
    int n = t0 + t;
    const float* xr = x + (size_t)n * DIM;
    float p[8] = {0.f, 0.f, 0.f, 0.f, 0.f, 0.f, 0.f, 0.f};
    #pragma unroll
    for (int it = 0; it < DIM / 64; ++it) {
      int d = lane + (it << 6);
      float xv = xr[d];
      const float4* g4 = (const float4*)(gW + (size_t)d * NE);
      float4 a = g4[0], b = g4[1];
      p[0] += xv * a.x; p[1] += xv * a.y; p[2] += xv * a.z; p[3] += xv * a.w;
      p[4] += xv * b.x; p[5] += xv * b.y; p[6] += xv * b.z; p[7] += xv * b.w;
    }
    #pragma unroll
    for (int e = 0; e < 8; ++e)
      for (int o = 32; o > 0; o >>= 1) p[e] += __shfl_down(p[e], o, 64);
    if (lane == 0) {
      float lg[8];
      #pragma unroll
      for (int e = 0; e < 8; ++e) lg[e] = p[e] + gb[e];
      int i0 = 0;
      #pragma unroll
      for (int e = 1; e < 8; ++e) if (lg[e] > lg[i0]) i0 = e;   // ties -> lowest idx
      int i1 = (i0 == 0) ? 1 : 0;
      #pragma unroll
      for (int e = 0; e < 8; ++e) if (e != i0 && lg[e] > lg[i1]) i1 = e;
      float d1 = expf(lg[i1] - lg[i0]);
      float g0 = 1.f / (1.f + d1);
      float g1 = d1 * g0;
      tok_e[2 * n] = i0; tok_e[2 * n + 1] = i1;
      tok_g[2 * n] = g0; tok_g[2 * n + 1] = g1;
      atomicAdd(&s_cnt[i0], 1);
      atomicAdd(&s_cnt[i1], 1);
      float mx = lg[i0], s = 0.f, pe[8];
      #pragma unroll
      for (int e = 0; e < 8; ++e) { pe[e] = expf(lg[e] - mx); s += pe[e]; }
      float inv = 1.f / s;
      #pragma unroll
      for (int e = 0; e < 8; ++e) {
        float pr = pe[e] * inv;
        imp_loc[e] += pr;
        ent_loc -= pr * logf(pr + 1e-8f);
      }
    }
  }
  if (lane == 0) {
    #pragma unroll
    for (int e = 0; e < 8; ++e) atomicAdd(&s_imp[e], imp_loc[e]);
    atomicAdd(&s_ent, ent_loc);
  }
  __syncthreads();
  const float invN = 1.f / (float)N_TOK;
  if (tid < NE) {
    atomicAdd(&cnt[tid], s_cnt[tid]);
    atomicAdd(&imp[tid], s_imp[tid] * invN);
  }
  if (tid == NE) atomicAdd(ent_sum, s_ent * invN);
}

// ---------------- finalize: padded offsets/cursors + scalar outputs ----------------
__global__ void finalize_kernel(const int* __restrict__ cnt, int* __restrict__ poffs,
                                int* __restrict__ cursor, const float* __restrict__ imp,
                                const float* __restrict__ ent_sum, float* __restrict__ out_tail) {
  if (threadIdx.x == 0) {
    int off = 0; float bal = 0.f, util = 0.f;
    for (int e = 0; e < NE; ++e) {
      poffs[e] = off; cursor[e] = off;
      off += ((cnt[e] + 127) >> 7) << 7;   // 128-aligned region per expert
      float ld = (float)cnt[e] * (1.f / (float)N_TOK);
      float im = imp[e];
      out_tail[3 + e] = ld;        // load
      out_tail[11 + e] = im;       // importance
      bal += im * ld;
      util -= ld * logf(ld + 1e-8f);
    }
    poffs[NE] = off;
    out_tail[0] = (float)NE * bal; // balance_loss
    out_tail[1] = *ent_sum;        // entropy
    out_tail[2] = util;            // utilization_entropy
  }
}

// ---------------- scatter pairs into (padded) expert buckets ----------------
__global__ __launch_bounds__(256) void scatter_kernel(
    const int* __restrict__ tok_e, const float* __restrict__ tok_g,
    int* __restrict__ cursor, int* __restrict__ row_token, float* __restrict__ row_gate,
    int* __restrict__ pair_slot) {
  __shared__ int s_cnt[NE], s_base[NE], s_rank[NE];
  int tid = threadIdx.x;
  if (tid < NE) { s_cnt[tid] = 0; s_rank[tid] = 0; }
  __syncthreads();
  int n = blockIdx.x * 256 + tid;
  int e0 = tok_e[2 * n], e1 = tok_e[2 * n + 1];
  atomicAdd(&s_cnt[e0], 1);
  atomicAdd(&s_cnt[e1], 1);
  __syncthreads();
  if (tid < NE) s_base[tid] = atomicAdd(&cursor[tid], s_cnt[tid]);
  __syncthreads();
  int r0 = atomicAdd(&s_rank[e0], 1);
  int s0 = s_base[e0] + r0;
  row_token[s0] = n; row_gate[s0] = tok_g[2 * n]; pair_slot[2 * n] = s0;
  int r1 = atomicAdd(&s_rank[e1], 1);
  int s1 = s_base[e1] + r1;
  row_token[s1] = n; row_gate[s1] = tok_g[2 * n + 1]; pair_slot[2 * n + 1] = s1;
}

// ---------------- gather bucketed A (x rows -> frag-chunk bf16, Kd=1024) ----------------
__global__ __launch_bounds__(256) void gather_a1(
    const float* __restrict__ x, const int* __restrict__ row_token,
    const int* __restrict__ cnt, const int* __restrict__ poffs,
    unsigned short* __restrict__ Ab1) {
  int e = blockIdx.z;
  int base = poffs[e];
  int pcnt = poffs[e + 1] - base;
  int nch = (pcnt >> 4) * 32;
  int cl = blockIdx.x * 4 + (threadIdx.x >> 6);
  if (cl >= nch) return;
  int lane = threadIdx.x & 63, m16 = lane & 15, q = lane >> 4;
  int rblk = cl >> 5, kblk = cl & 31;
  int sl = rblk * 16 + m16;
  int slot = base + sl;
  int tok = (sl < cnt[e]) ? row_token[slot] : 0;   // pad rows: token 0 (finite)
  int k = kblk * 32 + q * 8;
  const float4* sp = (const float4*)(x + (size_t)tok * DIM + k);
  float4 v0 = sp[0], v1 = sp[1];
  unsigned short t[8] = {f2bf(v0.x), f2bf(v0.y), f2bf(v0.z), f2bf(v0.w),
                         f2bf(v1.x), f2bf(v1.y), f2bf(v1.z), f2bf(v1.w)};
  *(uint4*)(Ab1 + ((size_t)(slot >> 4) * 32 + kblk) * 512 + lane * 8) = *(uint4*)t;
}

// ---------------- GEMM1: He = gelu(Ab1 @ W1f + b1), He in frag order (Kd=2048) ----------------
__global__ __launch_bounds__(256, 4) void expert_gemm1(
    const unsigned short* __restrict__ Ab1,   // frag, Kd32=32
    const unsigned short* __restrict__ W1f,   // [E] frag, rows=HID, Kd32=32
    const float* __restrict__ b1,             // [E][H]
    const int* __restrict__ poffs,
    unsigned short* __restrict__ He) {        // frag, rows=CAPP, Kd32=64
  __shared__ __align__(16) unsigned short As[8192], Bs[8192];
  int e = blockIdx.z;
  int base = poffs[e];
  int pcnt = poffs[e + 1] - base;
  int row0 = blockIdx.x * 128;
  if (row0 >= pcnt) return;
  int col0 = blockIdx.y * 128;
  int tid = threadIdx.x, wid = tid >> 6, lane = tid & 63;
  int m16 = lane & 15, q = lane >> 4;
  int wr = (wid & 1) << 6, wc = (wid >> 1) << 6;
  // wave wid stages row-blocks rb = wid*2 + {0,1}, each k-halves {0,1}
  const unsigned short* Ag = Ab1 + ((size_t)(((base + row0) >> 4) + wid * 2) * 32) * 512 + lane * 8;
  const unsigned short* Bg = W1f + (size_t)e * HID * DIM
                           + ((size_t)((col0 >> 4) + wid * 2) * 32) * 512 + lane * 8;
  unsigned short* lA = As + wid * 4 * 512;
  unsigned short* lB = Bs + wid * 4 * 512;
  f32x4_t zero4 = {0.f, 0.f, 0.f, 0.f};
  f32x4_t acc[4][4];
  #pragma unroll
  for (int i = 0; i < 4; ++i)
    #pragma unroll
    for (int j = 0; j < 4; ++j) acc[i][j] = zero4;
  int ra = wr >> 4, rc = wc >> 4;
  for (int k0 = 0; k0 < DIM; k0 += 64) {
    int kc = (k0 >> 5) * 512;
    load16_lds(Ag + kc,                  lA);
    load16_lds(Ag + kc + 512,            lA + 512);
    load16_lds(Ag + kc + 32 * 512,       lA + 1024);
    load16_lds(Ag + kc + 32 * 512 + 512, lA + 1536);
    load16_lds(Bg + kc,                  lB);
    load16_lds(Bg + kc + 512,            lB + 512);
    load16_lds(Bg + kc + 32 * 512,       lB + 1024);
    load16_lds(Bg + kc + 32 * 512 + 512, lB + 1536);
    __syncthreads();
    #pragma unroll
    for (int ks = 0; ks < 2; ++ks) {
      bf16x8_t a[4], b[4];
      #pragma unroll
      for (int i = 0; i < 4; ++i) {
        a[i] = *(const bf16x8_t*)&As[((ra + i) * 2 + ks) * 512 + lane * 8];
        b[i] = *(const bf16x8_t*)&Bs[((rc + i) * 2 + ks) * 512 + lane * 8];
      }
      #pragma unroll
      for (int i = 0; i < 4; ++i)
        #pragma unroll
        for (int j = 0; j < 4; ++j)
          acc[i][j] = __builtin_amdgcn_mfma_f32_16x16x32_bf16(a[i], b[j], acc[i][j], 0, 0, 0);
    }
    __syncthreads();
  }
  const float* b1e = b1 + (size_t)e * HID;
  int sb = (base + row0) >> 4;
  #pragma unroll
  for (int i = 0; i < 4; ++i) {
    size_t sblk = (size_t)(sb + ra + i);
    #pragma unroll
    for (int rr = 0; rr < 4; ++rr) {
      int s15 = q * 4 + rr;   // slot & 15
      #pragma unroll
      for (int j = 0; j < 4; ++j) {
        int col = col0 + wc + j * 16 + m16;
        float v = acc[i][j][rr] + b1e[col];
        size_t off = (sblk * 64 + (col >> 5)) * 512 + (((col >> 3) & 3) * 16 + s15) * 8 + (col & 7);
        He[off] = f2bf(gelu_exact(v));
      }
    }
  }
}

// ---------------- GEMM2: yb[slot] = He @ W2f (row-major out; bias+gate in LN) ----------------
__global__ __launch_bounds__(256, 4) void expert_gemm2(
    const unsigned short* __restrict__ He,    // frag, Kd32=64
    const unsigned short* __restrict__ W2f,   // [E] frag, rows=DIM, Kd32=64
    const int* __restrict__ poffs,
    unsigned short* __restrict__ yb) {        // [CAPP][DIM] row-major
  __shared__ __align__(16) unsigned short As[8192], Bs[8192];
  int e = blockIdx.z;
  int base = poffs[e];
  int pcnt = poffs[e + 1] - base;
  int row0 = blockIdx.x * 128;
  if (row0 >= pcnt) return;
  int col0 = blockIdx.y * 128;
  int tid = threadIdx.x, wid = tid >> 6, lane = tid & 63;
  int m16 = lane & 15, q = lane >> 4;
  int wr = (wid & 1) << 6, wc = (wid >> 1) << 6;
  const unsigned short* Ag = He + ((size_t)(((base + row0) >> 4) + wid * 2) * 64) * 512 + lane * 8;
  const unsigned short* Bg = W2f + (size_t)e * DIM * HID
                           + ((size_t)((col0 >> 4) + wid * 2) * 64) * 512 + lane * 8;
  unsigned short* lA = As + wid * 4 * 512;
  unsigned short* lB = Bs + wid * 4 * 512;
  f32x4_t zero4 = {0.f, 0.f, 0.f, 0.f};
  f32x4_t acc[4][4];
  #pragma unroll
  for (int i = 0; i < 4; ++i)
    #pragma unroll
    for (int j = 0; j < 4; ++j) acc[i][j] = zero4;
  int ra = wr >> 4, rc = wc >> 4;
  for (int k0 = 0; k0 < HID; k0 += 64) {
    int kc = (k0 >> 5) * 512;
    load16_lds(Ag + kc,                  lA);
    load16_lds(Ag + kc + 512,            lA + 512);
    load16_lds(Ag + kc + 64 * 512,       lA + 1024);
    load16_lds(Ag + kc + 64 * 512 + 512, lA + 1536);
    load16_lds(Bg + kc,                  lB);
    load16_lds(Bg + kc + 512,            lB + 512);
    load16_lds(Bg + kc + 64 * 512,       lB + 1024);
    load16_lds(Bg + kc + 64 * 512 + 512, lB + 1536);
    __syncthreads();
    #pragma unroll
    for (int ks = 0; ks < 2; ++ks) {
      bf16x8_t a[4], b[4];
      #pragma unroll
      for (int i = 0; i < 4; ++i) {
        a[i] = *(const bf16x8_t*)&As[((ra + i) * 2 + ks) * 512 + lane * 8];
        b[i] = *(const bf16x8_t*)&Bs[((rc + i) * 2 + ks) * 512 + lane * 8];
      }
      #pragma unroll
      for (int i = 0; i < 4; ++i)
        #pragma unroll
        for (int j = 0; j < 4; ++j)
          acc[i][j] = __builtin_amdgcn_mfma_f32_16x16x32_bf16(a[i], b[j], acc[i][j], 0, 0, 0);
    }
    __syncthreads();
  }
  #pragma unroll
  for (int i = 0; i < 4; ++i) {
    #pragma unroll
    for (int rr = 0; rr < 4; ++rr) {
      size_t slot = (size_t)(base + row0 + wr + i * 16 + q * 4 + rr);
      #pragma unroll
      for (int j = 0; j < 4; ++j) {
        int col = col0 + wc + j * 16 + m16;
        yb[slot * DIM + col] = f2bf(acc[i][j][rr]);
      }
    }
  }
}

// ---------------- gather + gate + bias + residual + LayerNorm ----------------
__global__ __launch_bounds__(256) void ln_kernel(
    const float* __restrict__ x, const unsigned short* __restrict__ yb,
    const int* __restrict__ tok_e, const float* __restrict__ tok_g,
    const int* __restrict__ pair_slot, const float* __restrict__ b2,
    const float* __restrict__ gamma, const float* __restrict__ beta,
    float* __restrict__ out) {
  int n = blockIdx.x, tid = threadIdx.x;
  int e0 = tok_e[2 * n], e1 = tok_e[2 * n + 1];
  float g0 = tok_g[2 * n], g1 = tok_g[2 * n + 1];
  size_t s0 = (size_t)pair_slot[2 * n], s1 = (size_t)pair_slot[2 * n + 1];
  const float* xr = x + (size_t)n * DIM;
  const unsigned short* y0 = yb + s0 * DIM;
  const unsigned short* y1 = yb + s1 * DIM;
  const float* b2e0 = b2 + (size_t)e0 * DIM;
  const float* b2e1 = b2 + (size_t)e1 * DIM;
  float z[4], s = 0.f, s2 = 0.f;
  #pragma unroll
  for (int jj = 0; jj < 4; ++jj) {
    int d = tid + (jj << 8);
    float v = xr[d] + g0 * (bf2f(y0[d]) + b2e0[d]) + g1 * (bf2f(y1[d]) + b2e1[d]);
    z[jj] = v; s += v; s2 += v * v;
  }
  for (int o = 32; o > 0; o >>= 1) { s += __shfl_down(s, o, 64); s2 += __shfl_down(s2, o, 64); }
  __shared__ float rs[4], rs2[4];
  int wid = tid >> 6, lane = tid & 63;
  if (lane == 0) { rs[wid] = s; rs2[wid] = s2; }
  __syncthreads();
  float ts = rs[0] + rs[1] + rs[2] + rs[3];
  float ts2 = rs2[0] + rs2[1] + rs2[2] + rs2[3];
  float mu = ts * (1.f / DIM);
  float var = ts2 * (1.f / DIM) - mu * mu;
  float rstd = rsqrtf(var + 1e-5f);
  float* orow = out + (size_t)n * DIM;
  #pragma unroll
  for (int jj = 0; jj < 4; ++jj) {
    int d = tid + (jj << 8);
    orow[d] = (z[jj] - mu) * rstd * gamma[d] + beta[d];
  }
}

extern "C" void kernel_launch(void* const* d_in, const int* in_sizes, int n_in,
                              void* d_out, int out_size, void* d_ws, size_t ws_size,
                              hipStream_t stream) {
  const float* x     = (const float*)d_in[0];
  const float* gW    = (const float*)d_in[1];
  const float* gb    = (const float*)d_in[2];
  const float* W1    = (const float*)d_in[3];
  const float* b1    = (const float*)d_in[4];
  const float* W2    = (const float*)d_in[5];
  const float* b2    = (const float*)d_in[6];
  const float* gamma = (const float*)d_in[7];
  const float* beta  = (const float*)d_in[8];
  float* out = (float*)d_out;

  // workspace layout (~166 MB), all chunks 16B-aligned
  char* w = (char*)d_ws;
  unsigned short* W1f = (unsigned short*)w; w += (size_t)NE * HID * DIM * 2;
  unsigned short* W2f = (unsigned short*)w; w += (size_t)NE * DIM * HID * 2;
  unsigned short* He  = (unsigned short*)w; w += (size_t)CAPP * HID * 2;
  unsigned short* AbY = (unsigned short*)w; w += (size_t)CAPP * DIM * 2;  // Ab1, then yb (aliased)
  int*   row_token    = (int*)w;            w += (size_t)CAPP * 4;
  float* row_gate     = (float*)w;          w += (size_t)CAPP * 4;
  int*   tok_e        = (int*)w;            w += (size_t)NPAIR * 4;
  float* tok_g        = (float*)w;          w += (size_t)NPAIR * 4;
  int*   pair_slot    = (int*)w;            w += (size_t)NPAIR * 4;
  float* imp          = (float*)w;          // 8 floats
  float* ent_sum      = imp + 8;            // 1 float (+7 pad)
  int*   cntp         = (int*)(imp + 16);   // 8 ints
  int*   cursor       = cntp + 8;           // 8 ints
  int*   poffs        = cursor + 8;         // 9 ints

  unsigned short* Ab1 = AbY;                // gemm1 input (dead after gemm1)
  unsigned short* yb  = AbY;                // gemm2 output (written after Ab1 dead)

  hipMemsetAsync(imp, 0, 256, stream);      // imp, ent_sum, cnt

  w_to_frag<DIM, HID><<<dim3(1024, 1, NE), 256, 0, stream>>>(W1, W1f);
  w_to_frag<HID, DIM><<<dim3(1024, 1, NE), 256, 0, stream>>>(W2, W2f);
  router_kernel<<<R_BLOCKS, 256, 0, stream>>>(x, gW, gb, tok_e, tok_g, cntp, imp, ent_sum);
  finalize_kernel<<<1, 64, 0, stream>>>(cntp, poffs, cursor, imp, ent_sum, out + TAIL);
  scatter_kernel<<<N_TOK / 256, 256, 0, stream>>>(tok_e, tok_g, cursor, row_token, row_gate, pair_slot);
  gather_a1<<<dim3(4096, 1, NE), 256, 0, stream>>>(x, row_token, cntp, poffs, Ab1);
  expert_gemm1<<<dim3(64, HID / 128, NE), 256, 0, stream>>>(Ab1, W1f, b1, poffs, He);
  expert_gemm2<<<dim3(64, DIM / 128, NE), 256, 0, stream>>>(He, W2f, poffs, yb);
  ln_kernel<<<N_TOK, 256, 0, stream>>>(x, yb, tok_e, tok_g, pair_slot, b2, gamma, beta, out);
}